// Round 3
// baseline (143.163 us; speedup 1.0000x reference)
//
#include <hip/hip_runtime.h>

#define TT 4096
#define DD 64
#define HH 12
#define LAMAX 256
#define KT 64
#define VS 68   // V^T row stride in shorts (measured: 0 bank conflicts)

typedef __attribute__((ext_vector_type(8))) short s8v;
typedef __attribute__((ext_vector_type(4))) short s4v;
typedef __attribute__((ext_vector_type(2))) short s2v;
typedef __attribute__((ext_vector_type(4))) float f4v;

static __device__ __forceinline__ short f2bf(float f) {
  unsigned u = __builtin_bit_cast(unsigned, f);
  u += 0x7FFFu + ((u >> 16) & 1u);   // RNE
  return (short)(u >> 16);
}

static __device__ __forceinline__ s8v pack8(float4 a, float4 b) {
  s8v r;
  r[0] = f2bf(a.x); r[1] = f2bf(a.y); r[2] = f2bf(a.z); r[3] = f2bf(a.w);
  r[4] = f2bf(b.x); r[5] = f2bf(b.y); r[6] = f2bf(b.z); r[7] = f2bf(b.w);
  return r;
}

static __device__ __forceinline__ s8v pack8s(float4 a, float4 b, float s) {
  s8v r;
  r[0] = f2bf(a.x * s); r[1] = f2bf(a.y * s); r[2] = f2bf(a.z * s); r[3] = f2bf(a.w * s);
  r[4] = f2bf(b.x * s); r[5] = f2bf(b.y * s); r[6] = f2bf(b.z * s); r[7] = f2bf(b.w * s);
  return r;
}

static __device__ __forceinline__ f4v MFMA16(s4v a, s4v b, f4v c) {
#if defined(__has_builtin) && __has_builtin(__builtin_amdgcn_mfma_f32_16x16x16bf16_1k)
  return __builtin_amdgcn_mfma_f32_16x16x16bf16_1k(a, b, c, 0, 0, 0);
#elif defined(__has_builtin) && __has_builtin(__builtin_amdgcn_mfma_f32_16x16x16_bf16)
  return __builtin_amdgcn_mfma_f32_16x16x16_bf16(a, b, c, 0, 0, 0);
#else
  asm("v_mfma_f32_16x16x16_bf16 %0, %1, %2, %0\n\ts_nop 7\n\ts_nop 7"
      : "+v"(c) : "v"(a), "v"(b));
  return c;
#endif
}

// 64 q-rows/block, 4 waves x 16 rows. KT=64 key tiles, LDS double-buffered,
// 1 barrier/iter, T14 async-stage split. Grid 1536 -> ~4 blocks/CU resident.
__global__ __launch_bounds__(256, 4)
void lma_attn_kernel(const float* __restrict__ Q, const float* __restrict__ K,
                     const float* __restrict__ V, const int* __restrict__ laPtr,
                     float* __restrict__ out)
{
  __shared__ short k_lds[2][64 * 64];   // bf16 K [j][d], b128 XOR swizzle
  __shared__ short vt_lds[2][64 * VS];  // bf16 V^T [d][j]

  const int tid  = threadIdx.x;
  const int lane = tid & 63;
  const int w    = tid >> 6;
  const int c    = lane & 15;
  const int g    = lane >> 4;

  // XCD-chunked bijective swizzle: grid = 1536 = 8 * 192.
  const int bid = blockIdx.x;
  const int wg  = (bid & 7) * 192 + (bid >> 3);
  const int bh  = wg >> 6;
  const int q0  = (wg & 63) << 6;
  const int la  = laPtr[0];

  const size_t base = (size_t)bh * (TT * DD);
  const int rb    = q0 + w * 16;        // wave's first row
  const int i_row = rb + c;

  // ---- Q fragment, pre-scaled by 1/sqrt(64)*log2(e) ----
  const float SCL = 0.125f * 1.44269504f;
  s8v qf[2];
  {
    const float* qp = Q + base + (size_t)i_row * DD + 8 * g;
    qf[0] = pack8s(*(const float4*)qp,        *(const float4*)(qp + 4),  SCL);
    qf[1] = pack8s(*(const float4*)(qp + 32), *(const float4*)(qp + 36), SCL);
  }

  // staging thread maps (block stages the full 64-key tile cooperatively)
  const int kj  = tid >> 2;          // K row 0..63
  const int kd0 = (tid & 3) << 4;    // K dim start
  const int vj0 = (tid & 31) << 1;   // V row pair
  const int vd0 = (tid >> 5) << 3;   // V dim start

  float4 kr0, kr1, kr2, kr3, vr0, vr1, vr2, vr3;
  auto stage_load = [&](int kj0) {
    const float* kp = K + base + (size_t)(kj0 + kj) * DD + kd0;
    kr0 = *(const float4*)kp;        kr1 = *(const float4*)(kp + 4);
    kr2 = *(const float4*)(kp + 8);  kr3 = *(const float4*)(kp + 12);
    const float* vp = V + base + (size_t)(kj0 + vj0) * DD + vd0;
    vr0 = *(const float4*)vp;        vr1 = *(const float4*)(vp + 4);
    vr2 = *(const float4*)(vp + DD); vr3 = *(const float4*)(vp + DD + 4);
  };
  auto stage_write = [&](int buf) {
    short* kb = (short*)k_lds[buf];
    const int sw = kj & 7, g8 = kd0 >> 3;
    *(s8v*)&kb[kj * 64 + ((g8    ) ^ sw) * 8] = pack8(kr0, kr1);
    *(s8v*)&kb[kj * 64 + ((g8 + 1) ^ sw) * 8] = pack8(kr2, kr3);
    short* vb = (short*)vt_lds[buf];
    const float a0[8] = {vr0.x, vr0.y, vr0.z, vr0.w, vr1.x, vr1.y, vr1.z, vr1.w};
    const float a1[8] = {vr2.x, vr2.y, vr2.z, vr2.w, vr3.x, vr3.y, vr3.z, vr3.w};
    #pragma unroll
    for (int e = 0; e < 8; ++e) {
      s2v pr; pr[0] = f2bf(a0[e]); pr[1] = f2bf(a1[e]);
      *(s2v*)&vb[(vd0 + e) * VS + vj0] = pr;
    }
  };

  f4v acc[4] = {};                   // out^T[d = 16dt+4g+r][q = c]
  float m2   = -1e30f;               // running max (log2 domain)
  float lsum = 0.f;

  const int t0 = (q0 >= LAMAX) ? 0 : ((LAMAX - q0) >> 6);

  stage_load(q0 - LAMAX + (t0 << 6));
  stage_write(t0 & 1);
  __syncthreads();

  for (int t = t0; t < 5; ++t) {
    const int kj0 = q0 - LAMAX + (t << 6);
    if (t < 4) stage_load(kj0 + KT);            // issue next-tile loads early

    const short* kb = (const short*)k_lds[t & 1];
    const short* vb = (const short*)vt_lds[t & 1];

    // wave-uniform activity (only t0-region blocks ever skip)
    if ((kj0 <= rb + 15) && (kj0 + KT >= rb - la + 2)) {
      // ---- S^T[j][q] = K * Q^T : 4 key-subtiles x K=64 ----
      f4v sa[4] = {};
      #pragma unroll
      for (int ch = 0; ch < 2; ++ch)
        #pragma unroll
        for (int ks = 0; ks < 4; ++ks) {
          s8v kf = *(const s8v*)&kb[(ks * 16 + c) * 64 + (((ch << 2) + g) ^ (c & 7)) * 8];
          sa[ks] = __builtin_amdgcn_mfma_f32_16x16x32_bf16(kf, qf[ch], sa[ks], 0, 0, 0);
        }

      // ---- mask (specialized per tile class) + row max ----
      const bool needC = (kj0 + 63 > rb);            // diagonal tile
      const bool needL = (kj0 < rb + 16 - la);       // left-edge tile
      const int jrel = kj0 - rb;                     // jt - i_row = jrel + off - c
      const int jloR = i_row - la + 1;
      float p[4][4];
      #define MASKMAX(NC, NL)                                              \
        _Pragma("unroll")                                                  \
        for (int ks = 0; ks < 4; ++ks)                                     \
          _Pragma("unroll")                                                \
          for (int r = 0; r < 4; ++r) {                                    \
            float s = sa[ks][r];                                           \
            if (NC || NL) {                                                \
              const int jt = kj0 + ks * 16 + 4 * g + r;                    \
              bool ok = true;                                              \
              if (NC) ok = (jt <= i_row);                                  \
              if (NL) ok = ok && (jt >= jloR);                             \
              s = ok ? s : -1e30f;                                         \
            }                                                              \
            p[ks][r] = s;                                                  \
          }
      if (needC) { if (needL) { MASKMAX(true, true) } else { MASKMAX(true, false) } }
      else       { if (needL) { MASKMAX(false, true) } else { MASKMAX(false, false) } }
      #undef MASKMAX
      (void)jrel;

      // tree max over 16 (max3-fusable) + 2 shfl
      float t0a = fmaxf(fmaxf(p[0][0], p[0][1]), fmaxf(p[0][2], p[0][3]));
      float t1a = fmaxf(fmaxf(p[1][0], p[1][1]), fmaxf(p[1][2], p[1][3]));
      float t2a = fmaxf(fmaxf(p[2][0], p[2][1]), fmaxf(p[2][2], p[2][3]));
      float t3a = fmaxf(fmaxf(p[3][0], p[3][1]), fmaxf(p[3][2], p[3][3]));
      float tmax = fmaxf(fmaxf(t0a, t1a), fmaxf(t2a, t3a));
      tmax = fmaxf(tmax, __shfl_xor(tmax, 16, 64));
      tmax = fmaxf(tmax, __shfl_xor(tmax, 32, 64));

      // ---- T13 defer-max: rescale only when max grows past THR ----
      if (!__all(tmax <= m2 + 8.0f)) {
        const float mn = fmaxf(m2, tmax);
        const float corr = exp2f(m2 - mn);   // junk epoch -> corr = 0 wipes acc/lsum
        m2 = mn;
        lsum *= corr;
        #pragma unroll
        for (int dt = 0; dt < 4; ++dt) {
          acc[dt][0] *= corr; acc[dt][1] *= corr;
          acc[dt][2] *= corr; acc[dt][3] *= corr;
        }
      }

      // ---- exp2 + pack; sum tree off critical path ----
      s4v pb[4]; float e[4][4];
      #pragma unroll
      for (int ks = 0; ks < 4; ++ks)
        #pragma unroll
        for (int r = 0; r < 4; ++r) {
          e[ks][r] = exp2f(p[ks][r] - m2);
          pb[ks][r] = f2bf(e[ks][r]);
        }

      // ---- PV: out^T += V^T * P^T (16x16x16: P layout matches B operand) ----
      #pragma unroll
      for (int dt = 0; dt < 4; ++dt) {
        const int d = dt * 16 + c;
        #pragma unroll
        for (int sub = 0; sub < 4; ++sub) {
          s4v vf = *(const s4v*)&vb[d * VS + sub * 16 + g * 4];
          acc[dt] = MFMA16(vf, pb[sub], acc[dt]);
        }
      }

      float s0 = (e[0][0] + e[0][1]) + (e[0][2] + e[0][3]);
      float s1 = (e[1][0] + e[1][1]) + (e[1][2] + e[1][3]);
      float s2 = (e[2][0] + e[2][1]) + (e[2][2] + e[2][3]);
      float s3 = (e[3][0] + e[3][1]) + (e[3][2] + e[3][3]);
      float ps = (s0 + s1) + (s2 + s3);
      ps += __shfl_xor(ps, 16, 64);
      ps += __shfl_xor(ps, 32, 64);
      lsum += ps;
    }

    if (t < 4) stage_write((t + 1) & 1);        // write late, after compute
    __syncthreads();                            // single barrier per iteration
  }

  // ---- epilogue: lane owns one q-row; lanes g=0..3 tile a 64B line per dt ----
  const float inv = 1.f / lsum;
  float* op = out + ((size_t)(bh / HH) * TT + i_row) * (HH * DD) + (bh % HH) * DD + 4 * g;
  #pragma unroll
  for (int dt = 0; dt < 4; ++dt) {
    float4 o;
    o.x = acc[dt][0] * inv; o.y = acc[dt][1] * inv;
    o.z = acc[dt][2] * inv; o.w = acc[dt][3] * inv;
    *(float4*)(op + dt * 16) = o;
  }
}

extern "C" void kernel_launch(void* const* d_in, const int* in_sizes, int n_in,
                              void* d_out, int out_size, void* d_ws, size_t ws_size,
                              hipStream_t stream) {
  const float* q = (const float*)d_in[0];
  const float* k = (const float*)d_in[1];
  const float* v = (const float*)d_in[2];
  const int* la = (const int*)d_in[3];
  float* out = (float*)d_out;
  (void)in_sizes; (void)n_in; (void)out_size; (void)d_ws; (void)ws_size;

  dim3 grid(24 * 64);   // 64-row q-tiles; 6 blocks/CU by grid, ~4 resident (LDS)
  dim3 block(256);
  lma_attn_kernel<<<grid, block, 0, stream>>>(q, k, v, la, out);
}